// Round 7
// baseline (94.475 us; speedup 1.0000x reference)
//
#include <hip/hip_runtime.h>
#include <math.h>

#define BATCH 64
#define A_TOTAL 8649
#define PRE 1000
#define POST 256
#define NBINS 4096
#define NW 16              // 1000 bits -> 16 u64 words
#define TRIG 120           // upper-tri-minus-diag column groups: sum_{I=0..14}(15-I)
#define TRIP 65            // padded group stride (bank-conflict-free flush reads)
#define TRI_WORDS (TRIG * TRIP)   // 7800 u64 per batch

// ---------------- K1: per-batch exact top-1000 + box decode ----------------
// Histogram -> per-bin exact suffix counts (exc) -> threshold bin -> bin-grouped
// compaction -> rank = exc[bin] + within-bin count (segments small) -> decode
// + scatter to tboxes/tscores[b][rank]. Keys unique -> deterministic.
__global__ __launch_bounds__(1024) void k_topk_decode(
    const float* __restrict__ deltas,   // [B][A][4]
    const float* __restrict__ probs,    // [B][A]
    const float* __restrict__ anchors,  // [A][4] yxyx
    float4* __restrict__ tboxes,        // [B][PRE]
    float* __restrict__ tscores)        // [B][PRE]
{
    #pragma clang fp contract(off)
    const int b = blockIdx.x;
    const int t = threadIdx.x;
    __shared__ unsigned int hist[NBINS];   // reused as per-bin scatter counters
    __shared__ unsigned int exc[NBINS];    // # anchors with bin' > bin
    __shared__ unsigned int sbits[A_TOTAL];
    __shared__ unsigned long long cand[2048];
    __shared__ unsigned int gsum[256];
    __shared__ unsigned int s_thr;
    __shared__ unsigned int s_n;

    for (int i = t; i < NBINS; i += 1024) hist[i] = 0u;
    __syncthreads();

    const float* pr = probs + (size_t)b * A_TOTAL;
    for (int i = t; i < A_TOTAL; i += 1024) {
        unsigned int bits = __float_as_uint(pr[i]);   // probs in [0,1): bit order == value order
        sbits[i] = bits;
        atomicAdd(&hist[bits >> 18], 1u);
    }
    __syncthreads();

    // 16-bin group partial sums
    if (t < 256) {
        unsigned int gs = 0;
        #pragma unroll
        for (int q = 0; q < 16; ++q) gs += hist[t * 16 + q];
        gsum[t] = gs;
    }
    __syncthreads();
    // single-wave inclusive suffix scan over 256 groups (4 groups per lane)
    if (t < 64) {
        const int l = t;
        unsigned int a  = gsum[4 * l];
        unsigned int b2 = gsum[4 * l + 1];
        unsigned int c  = gsum[4 * l + 2];
        unsigned int d  = gsum[4 * l + 3];
        unsigned int quad = a + b2 + c + d;
        unsigned int q = quad;
        #pragma unroll
        for (int off = 1; off < 64; off <<= 1) {
            unsigned int v = __shfl_down(q, off);
            q += (l + off < 64) ? v : 0u;
        }
        gsum[4 * l]     = q;
        gsum[4 * l + 1] = q - a;
        gsum[4 * l + 2] = q - a - b2;
        gsum[4 * l + 3] = q - a - b2 - c;
    }
    __syncthreads();
    // per-bin exclusive suffix counts
    if (t < 256) {
        unsigned int run = (t == 255) ? 0u : gsum[t + 1];
        for (int q = 15; q >= 0; --q) {
            int bin = t * 16 + q;
            exc[bin] = run;
            run += hist[bin];
        }
    }
    __syncthreads();
    // threshold bin T = max bin with (exc+hist) >= PRE; n = candidates at/above T
    for (int bin = t; bin < NBINS; bin += 1024) {
        unsigned int ge = exc[bin] + hist[bin];
        unsigned int ge1 = (bin == NBINS - 1) ? 0u : (exc[bin + 1] + hist[bin + 1]);
        if (ge >= PRE && ge1 < PRE) { s_thr = (unsigned int)bin; s_n = ge; }
    }
    __syncthreads();
    const unsigned int T = s_thr;
    const int n = (s_n > 2048u) ? 2048 : (int)s_n;
    // reuse hist as per-bin scatter counters
    for (int i = t; i < NBINS; i += 1024) hist[i] = 0u;
    __syncthreads();

    // bin-grouped compaction: bin k's candidates land in [exc[k], exc[k]+cnt[k])
    for (int i = t; i < A_TOTAL; i += 1024) {
        unsigned int bits = sbits[i];
        unsigned int bin = bits >> 18;
        if (bin >= T) {
            unsigned int p = exc[bin] + atomicAdd(&hist[bin], 1u);
            if (p < 2048u)
                cand[p] = ((unsigned long long)bits << 32) |
                          (unsigned long long)(0xFFFFFFFFu - (unsigned int)i);
        }
    }
    __syncthreads();

    // rank within segment + decode + scatter
    const float4* anc4 = (const float4*)anchors;
    const float4* dl4  = (const float4*)(deltas + (size_t)b * A_TOTAL * 4);
    for (int p = t; p < n; p += 1024) {
        unsigned long long key = cand[p];
        unsigned int bin = (unsigned int)(key >> 50);       // score_bits >> 18
        int segs = (int)exc[bin];
        int sege = (bin > 0) ? (int)exc[bin - 1] : n;       // exc[b-1] == exc[b]+hist_orig[b]
        if (sege > 2048) sege = 2048;
        unsigned int rank = (unsigned int)segs;
        for (int q = segs; q < sege; ++q) rank += (cand[q] > key);
        if (rank >= PRE) continue;
        unsigned int idx = 0xFFFFFFFFu - (unsigned int)(key & 0xFFFFFFFFull);
        float sc = __uint_as_float((unsigned int)(key >> 32));
        float4 a = anc4[idx];
        float4 d = dl4[idx];
        float ah  = a.z - a.x;
        float aw  = a.w - a.y;
        float acy = a.x + 0.5f * ah;
        float acx = a.y + 0.5f * aw;
        float ty = d.x * 0.1f, tx = d.y * 0.1f, th = d.z * 0.2f, tw = d.w * 0.2f;
        float h = (float)exp((double)th) * ah;
        float w = (float)exp((double)tw) * aw;
        float cy = ty * ah + acy;
        float cx = tx * aw + acx;
        float4 bx = make_float4(cy - 0.5f * h, cx - 0.5f * w, cy + 0.5f * h, cx + 0.5f * w);
        tboxes[(size_t)b * PRE + rank] = bx;
        tscores[(size_t)b * PRE + rank] = sc;
    }
}

// ---------------- K2: suppression bitmask build (register-j + readlane) ----------------
// lane = i-row; lane l also holds j-box (Jbase+l) in registers (one coalesced
// float4 load). Per jj the j-side is broadcast via v_readlane with a UNIFORM
// SGPR loop index (no waterfall, no DS, no per-jj VMEM). Areas computed in VALU.
// Off-diag tile (I,W) -> mtri[b][(CG(I)+(W-I-1))*65+lane]; diag -> mdiag[b][W*64+lane].
// Decision equivalence: RN(inter/u) > 0.8f  <=>  inter >= (0.8f + 2^-25) * u
// (0.8f has odd mantissa -> halfway rounds up; 25x24-bit double product exact).
__global__ __launch_bounds__(256) void k_masks(
    const float4* __restrict__ tboxes,          // [B][PRE]
    unsigned long long* __restrict__ mtri,      // [B][TRI_WORDS]
    unsigned long long* __restrict__ mdiag)     // [B][NW*64]
{
    #pragma clang fp contract(off)
    const int b = blockIdx.y;
    // tile id -> (I, W), upper triangle row-major: I has (16-I) tiles
    int f = blockIdx.x * 4 + (threadIdx.x >> 6);
    f = __builtin_amdgcn_readfirstlane(f);      // pin wave-uniform -> SGPR
    int I = 0;
    while (f >= 16 - I) { f -= 16 - I; ++I; }
    const int W = I + f;
    const int lane = threadIdx.x & 63;
    const int row = (I << 6) + lane;
    const int rr = (row < PRE) ? row : (PRE - 1);
    const float4 bi = tboxes[(size_t)b * PRE + rr];
    const float areai = (bi.z - bi.x) * (bi.w - bi.y);
    const int Jbase = W << 6;
    const int jr = Jbase + lane;
    const int jrr = (jr < PRE) ? jr : (PRE - 1);
    const float4 bjv = tboxes[(size_t)b * PRE + jrr];      // lane l holds box Jbase+l
    const float areajv = (bjv.z - bjv.x) * (bjv.w - bjv.y);
    const int jmax = (PRE - Jbase < 64) ? (PRE - Jbase) : 64;
    const double C = (double)0.8f + 0x1p-25;
    const bool diag = (I == W);
    unsigned int mlo = 0u, mhi = 0u;

    #pragma unroll 4
    for (int jj = 0; jj < jmax; ++jj) {
        float sx = __int_as_float(__builtin_amdgcn_readlane(__float_as_int(bjv.x), jj));
        float sy = __int_as_float(__builtin_amdgcn_readlane(__float_as_int(bjv.y), jj));
        float sz = __int_as_float(__builtin_amdgcn_readlane(__float_as_int(bjv.z), jj));
        float sw = __int_as_float(__builtin_amdgcn_readlane(__float_as_int(bjv.w), jj));
        float sa = __int_as_float(__builtin_amdgcn_readlane(__float_as_int(areajv), jj));
        float y1 = fmaxf(bi.x, sx);
        float x1 = fmaxf(bi.y, sy);
        float y2 = fminf(bi.z, sz);
        float x2 = fminf(bi.w, sw);
        float inter = fmaxf(y2 - y1, 0.0f) * fmaxf(x2 - x1, 0.0f);
        float uni = (areai + sa) - inter;            // same assoc as reference
        float u = fmaxf(uni, 1e-8f);
        bool sup = ((double)inter >= C * (double)u); // == (inter/u > 0.8f) exactly
        if (diag) sup = sup && (lane < jj);          // strict j > i on diagonal
        unsigned int s = sup ? 1u : 0u;
        if (jj < 32) mlo |= (s << jj); else mhi |= (s << (jj - 32));  // uniform branch
    }

    const unsigned long long mword =
        ((unsigned long long)mhi << 32) | (unsigned long long)mlo;
    if (row < PRE) {
        if (diag) {
            mdiag[((size_t)b << 10) + (W << 6) + lane] = mword;
        } else {
            const int cg = 15 * I - (I * (I - 1)) / 2 + (W - I - 1);
            mtri[(size_t)b * TRI_WORDS + (size_t)cg * TRIP + lane] = mword;
        }
    }
}

// ---------------- K3: ffs-driven greedy scan + output ----------------
// Stage tri (62.4KB) + diag (8KB) mask blocks into LDS with linear float4 copies.
// Wave0 scans: first alive row is always kept -> iterate only kept rows (<=256,
// early stop). Flush reads kept rows from sidx (LDS) -> pure LDS gathers; all
// readlane indices are uniform (literal or readfirstlane'd) -> no waterfalls.
__global__ __launch_bounds__(512) void k_nms_out(
    const float4* __restrict__ tboxes,
    const float* __restrict__ tscores,
    const unsigned long long* __restrict__ mtri,
    const unsigned long long* __restrict__ mdiag,
    float* __restrict__ out)   // [B*POST*4] boxes then [B*POST] scores
{
    #pragma clang fp contract(off)
    const int b = blockIdx.x;
    const int tid = threadIdx.x;
    __shared__ __align__(16) unsigned long long Ml[TRI_WORDS];   // 62,400 B
    __shared__ __align__(16) unsigned long long Mdl[NW * 64];    //  8,192 B
    __shared__ int sidx[POST];
    __shared__ int s_kc;

    // wave0: diagonal words into registers (coalesced 512B loads; scan-path readlane)
    unsigned int dlo[NW], dhi[NW];
    if (tid < 64) {
        const unsigned long long* Db = mdiag + ((size_t)b << 10);
        #pragma unroll
        for (int W = 0; W < NW; ++W) {
            const int base = W << 6;
            const int nvalid = (PRE - base < 64) ? (PRE - base) : 64;
            unsigned long long dv = Db[base + tid];
            if (tid >= nvalid) dv = 0ull;
            dlo[W] = (unsigned int)dv;
            dhi[W] = (unsigned int)(dv >> 32);
        }
    }

    // all threads: linear coalesced staging of tri + diag blocks
    {
        const float4* src = (const float4*)(mtri + (size_t)b * TRI_WORDS);
        float4* dst = (float4*)Ml;
        for (int i = tid; i < TRI_WORDS / 2; i += 512) dst[i] = src[i];
        const float4* src2 = (const float4*)(mdiag + ((size_t)b << 10));
        float4* dst2 = (float4*)Mdl;
        for (int i = tid; i < (NW * 64) / 2; i += 512) dst2[i] = src2[i];
    }
    __syncthreads();

    if (tid < 64) {
        const int lane = tid;
        const int wword = lane & 15;
        const int wgrp  = lane >> 4;
        unsigned long long rm = 0ull;   // distributed removed word (l&15), group partial
        int kc = 0;
        bool done = false;
        #pragma unroll
        for (int W = 0; W < NW; ++W) {
            const int base = W << 6;
            // merge the 4 group partials of removed word W -> uniform (literal lane idx)
            unsigned int rlo = (unsigned int)__builtin_amdgcn_readlane((int)(unsigned int)rm, W)
                             | (unsigned int)__builtin_amdgcn_readlane((int)(unsigned int)rm, W + 16)
                             | (unsigned int)__builtin_amdgcn_readlane((int)(unsigned int)rm, W + 32)
                             | (unsigned int)__builtin_amdgcn_readlane((int)(unsigned int)rm, W + 48);
            unsigned int rhi = (unsigned int)__builtin_amdgcn_readlane((int)(unsigned int)(rm >> 32), W)
                             | (unsigned int)__builtin_amdgcn_readlane((int)(unsigned int)(rm >> 32), W + 16)
                             | (unsigned int)__builtin_amdgcn_readlane((int)(unsigned int)(rm >> 32), W + 32)
                             | (unsigned int)__builtin_amdgcn_readlane((int)(unsigned int)(rm >> 32), W + 48);
            unsigned long long rmW = ((unsigned long long)rhi << 32) | (unsigned long long)rlo;
            unsigned long long valid = (PRE - base >= 64) ? ~0ull : ((1ull << (PRE - base)) - 1ull);
            unsigned long long alive = ~rmW & valid;
            const int k0 = kc;
            while (alive) {
                int i = __builtin_amdgcn_readfirstlane(__ffsll(alive) - 1);  // uniform
                if (lane == 0) sidx[kc] = base + i;
                ++kc;
                if (kc == POST) { done = true; break; }
                unsigned int dl = (unsigned int)__builtin_amdgcn_readlane((int)dlo[W], i);
                unsigned int dh = (unsigned int)__builtin_amdgcn_readlane((int)dhi[W], i);
                unsigned long long d = ((unsigned long long)dh << 32) | (unsigned long long)dl;
                alive &= ~(d | (1ull << i));
            }
            if (done) break;
            // flush kept rows sidx[k0..kc): 4 rows/round (one per group), pure LDS
            const int cgW = 15 * W - (W * (W - 1)) / 2;   // compile-time (W unrolled)
            for (int fp = k0; fp < kc; fp += 4) {
                const int idx = fp + wgrp;
                unsigned long long m = 0ull;
                if (idx < kc) {
                    const int ii = sidx[idx] & 63;
                    if (wword > W)       m = Ml[(cgW + wword - W - 1) * TRIP + ii];
                    else if (wword == W) m = Mdl[(W << 6) + ii];
                }
                rm |= m;
            }
        }
        if (lane == 0) s_kc = kc;
    }
    __syncthreads();

    const int kc = s_kc;
    const float4* bb = tboxes + (size_t)b * PRE;
    const float* ss = tscores + (size_t)b * PRE;
    float4* oB = (float4*)out + (size_t)b * POST;
    float* oS = out + (size_t)BATCH * POST * 4 + (size_t)b * POST;
    for (int t2 = tid; t2 < POST; t2 += 512) {
        float4 v = make_float4(0.f, 0.f, 0.f, 0.f);
        float sc = 0.f;
        if (t2 < kc) {
            int r = sidx[t2];
            float4 bx = bb[r];
            v.x = fminf(fmaxf(bx.x, 0.f), 1.f);
            v.y = fminf(fmaxf(bx.y, 0.f), 1.f);
            v.z = fminf(fmaxf(bx.z, 0.f), 1.f);
            v.w = fminf(fmaxf(bx.w, 0.f), 1.f);
            sc = ss[r];
        }
        oB[t2] = v;
        oS[t2] = sc;
    }
}

extern "C" void kernel_launch(void* const* d_in, const int* in_sizes, int n_in,
                              void* d_out, int out_size, void* d_ws, size_t ws_size,
                              hipStream_t stream) {
    const float* deltas  = (const float*)d_in[0];   // [64,8649,4] f32
    const float* probs   = (const float*)d_in[1];   // [64,8649]   f32
    const float* anchors = (const float*)d_in[3];   // [8649,4]    f32
    float* out = (float*)d_out;

    char* ws = (char*)d_ws;
    float4* tboxes = (float4*)ws;                                    // 1,024,000 B
    float* tscores = (float*)(ws + 1024000);                         //   256,000 B
    unsigned long long* mdiag = (unsigned long long*)(ws + 1280000); //   524,288 B
    unsigned long long* mtri  = (unsigned long long*)(ws + 1804288); // 3,993,600 B

    k_topk_decode<<<dim3(BATCH), dim3(1024), 0, stream>>>(deltas, probs, anchors,
                                                          tboxes, tscores);
    k_masks<<<dim3(34, BATCH), dim3(256), 0, stream>>>(tboxes, mtri, mdiag);
    k_nms_out<<<dim3(BATCH), dim3(512), 0, stream>>>(tboxes, tscores, mtri, mdiag, out);
}

// Round 8
// 91.676 us; speedup vs baseline: 1.0305x; 1.0305x over previous
//
#include <hip/hip_runtime.h>
#include <math.h>

#define BATCH 64
#define A_TOTAL 8649
#define PRE 1000
#define POST 256
#define NBINS 4096
#define NW 16              // 1000 bits -> 16 u64 words
#define TRIG 120           // upper-tri-minus-diag column groups: sum_{I=0..14}(15-I)
#define TRIP 65            // padded group stride (bank-conflict-free flush reads)
#define TRI_WORDS (TRIG * TRIP)   // 7800 u64 per batch

// ---------------- K1: per-batch exact top-1000 + box decode ----------------
// Histogram -> per-bin exact suffix counts (exc) -> threshold bin -> bin-grouped
// compaction -> rank = exc[bin] + within-bin count (segments small) -> decode
// + scatter to tboxes/tscores[b][rank]. Keys unique -> deterministic.
__global__ __launch_bounds__(1024) void k_topk_decode(
    const float* __restrict__ deltas,   // [B][A][4]
    const float* __restrict__ probs,    // [B][A]
    const float* __restrict__ anchors,  // [A][4] yxyx
    float4* __restrict__ tboxes,        // [B][PRE]
    float* __restrict__ tscores)        // [B][PRE]
{
    #pragma clang fp contract(off)
    const int b = blockIdx.x;
    const int t = threadIdx.x;
    __shared__ unsigned int hist[NBINS];   // reused as per-bin scatter counters
    __shared__ unsigned int exc[NBINS];    // # anchors with bin' > bin
    __shared__ unsigned int sbits[A_TOTAL];
    __shared__ unsigned long long cand[2048];
    __shared__ unsigned int gsum[256];
    __shared__ unsigned int s_thr;
    __shared__ unsigned int s_n;

    for (int i = t; i < NBINS; i += 1024) hist[i] = 0u;
    __syncthreads();

    const float* pr = probs + (size_t)b * A_TOTAL;
    for (int i = t; i < A_TOTAL; i += 1024) {
        unsigned int bits = __float_as_uint(pr[i]);   // probs in [0,1): bit order == value order
        sbits[i] = bits;
        atomicAdd(&hist[bits >> 18], 1u);
    }
    __syncthreads();

    // 16-bin group partial sums
    if (t < 256) {
        unsigned int gs = 0;
        #pragma unroll
        for (int q = 0; q < 16; ++q) gs += hist[t * 16 + q];
        gsum[t] = gs;
    }
    __syncthreads();
    // single-wave inclusive suffix scan over 256 groups (4 groups per lane)
    if (t < 64) {
        const int l = t;
        unsigned int a  = gsum[4 * l];
        unsigned int b2 = gsum[4 * l + 1];
        unsigned int c  = gsum[4 * l + 2];
        unsigned int d  = gsum[4 * l + 3];
        unsigned int quad = a + b2 + c + d;
        unsigned int q = quad;
        #pragma unroll
        for (int off = 1; off < 64; off <<= 1) {
            unsigned int v = __shfl_down(q, off);
            q += (l + off < 64) ? v : 0u;
        }
        gsum[4 * l]     = q;
        gsum[4 * l + 1] = q - a;
        gsum[4 * l + 2] = q - a - b2;
        gsum[4 * l + 3] = q - a - b2 - c;
    }
    __syncthreads();
    // per-bin exclusive suffix counts
    if (t < 256) {
        unsigned int run = (t == 255) ? 0u : gsum[t + 1];
        for (int q = 15; q >= 0; --q) {
            int bin = t * 16 + q;
            exc[bin] = run;
            run += hist[bin];
        }
    }
    __syncthreads();
    // threshold bin T = max bin with (exc+hist) >= PRE; n = candidates at/above T
    for (int bin = t; bin < NBINS; bin += 1024) {
        unsigned int ge = exc[bin] + hist[bin];
        unsigned int ge1 = (bin == NBINS - 1) ? 0u : (exc[bin + 1] + hist[bin + 1]);
        if (ge >= PRE && ge1 < PRE) { s_thr = (unsigned int)bin; s_n = ge; }
    }
    __syncthreads();
    const unsigned int T = s_thr;
    const int n = (s_n > 2048u) ? 2048 : (int)s_n;
    // reuse hist as per-bin scatter counters
    for (int i = t; i < NBINS; i += 1024) hist[i] = 0u;
    __syncthreads();

    // bin-grouped compaction: bin k's candidates land in [exc[k], exc[k]+cnt[k])
    for (int i = t; i < A_TOTAL; i += 1024) {
        unsigned int bits = sbits[i];
        unsigned int bin = bits >> 18;
        if (bin >= T) {
            unsigned int p = exc[bin] + atomicAdd(&hist[bin], 1u);
            if (p < 2048u)
                cand[p] = ((unsigned long long)bits << 32) |
                          (unsigned long long)(0xFFFFFFFFu - (unsigned int)i);
        }
    }
    __syncthreads();

    // rank within segment + decode + scatter
    const float4* anc4 = (const float4*)anchors;
    const float4* dl4  = (const float4*)(deltas + (size_t)b * A_TOTAL * 4);
    for (int p = t; p < n; p += 1024) {
        unsigned long long key = cand[p];
        unsigned int bin = (unsigned int)(key >> 50);       // score_bits >> 18
        int segs = (int)exc[bin];
        int sege = (bin > 0) ? (int)exc[bin - 1] : n;       // exc[b-1] == exc[b]+hist_orig[b]
        if (sege > 2048) sege = 2048;
        unsigned int rank = (unsigned int)segs;
        for (int q = segs; q < sege; ++q) rank += (cand[q] > key);
        if (rank >= PRE) continue;
        unsigned int idx = 0xFFFFFFFFu - (unsigned int)(key & 0xFFFFFFFFull);
        float sc = __uint_as_float((unsigned int)(key >> 32));
        float4 a = anc4[idx];
        float4 d = dl4[idx];
        float ah  = a.z - a.x;
        float aw  = a.w - a.y;
        float acy = a.x + 0.5f * ah;
        float acx = a.y + 0.5f * aw;
        float ty = d.x * 0.1f, tx = d.y * 0.1f, th = d.z * 0.2f, tw = d.w * 0.2f;
        float h = (float)exp((double)th) * ah;
        float w = (float)exp((double)tw) * aw;
        float cy = ty * ah + acy;
        float cx = tx * aw + acx;
        float4 bx = make_float4(cy - 0.5f * h, cx - 0.5f * w, cy + 0.5f * h, cx + 0.5f * w);
        tboxes[(size_t)b * PRE + rank] = bx;
        tscores[(size_t)b * PRE + rank] = sc;
    }
}

// ---------------- K2: suppression bitmask build (2 rows/lane + readlane) ----------------
// Tile = 128 i-rows x 64 j. Lane l owns rows r0=RG*128+l and r1=r0+64, plus j-box
// Jbase+l in registers. Per jj the j-side (4 coords + area) is broadcast via
// v_readlane with a uniform index and reused for BOTH rows -> broadcast + loop
// overhead amortize over 128 pairs. Tiles with the whole r1 range sub-diagonal
// (W==2RG) skip r1. Store layout identical to previous rounds (mtri/mdiag).
// Decision equivalence: RN(inter/u) > 0.8f  <=>  inter >= (0.8f + 2^-25) * u
// (0.8f has odd mantissa -> halfway rounds up; 25x24-bit double product exact).
__global__ __launch_bounds__(256) void k_masks(
    const float4* __restrict__ tboxes,          // [B][PRE]
    unsigned long long* __restrict__ mtri,      // [B][TRI_WORDS]
    unsigned long long* __restrict__ mdiag)     // [B][NW*64]
{
    #pragma clang fp contract(off)
    const int b = blockIdx.y;
    // tile id -> (RG, W): row-group RG (128 rows) has words W = 2RG..15 (16-2RG tiles)
    int f = blockIdx.x * 4 + (threadIdx.x >> 6);
    f = __builtin_amdgcn_readfirstlane(f);      // pin wave-uniform -> SGPR
    int RG = 0;
    while (f >= 16 - 2 * RG) { f -= 16 - 2 * RG; ++RG; }
    const int W = 2 * RG + f;
    const int lane = threadIdx.x & 63;
    const int r0 = (RG << 7) + lane;            // <= 959, always valid
    const int r1 = r0 + 64;
    const bool d0 = (W == 2 * RG);              // r0's diagonal word
    const bool d1 = (W == 2 * RG + 1);          // r1's diagonal word
    const bool evalR1 = !d0;                    // W==2RG -> r1 all sub-diagonal

    const float4 b0 = tboxes[(size_t)b * PRE + r0];
    const float a0 = (b0.z - b0.x) * (b0.w - b0.y);
    const int r1c = (r1 < PRE) ? r1 : (PRE - 1);
    const float4 b1 = tboxes[(size_t)b * PRE + r1c];
    const float a1 = (b1.z - b1.x) * (b1.w - b1.y);

    const int Jbase = W << 6;
    const int jr = Jbase + lane;
    const float4 bjv = tboxes[(size_t)b * PRE + ((jr < PRE) ? jr : (PRE - 1))];
    const float av = (bjv.z - bjv.x) * (bjv.w - bjv.y);
    const int jmax = (PRE - Jbase < 64) ? (PRE - Jbase) : 64;

    const double C = (double)0.8f + 0x1p-25;
    unsigned int m0lo = 0u, m0hi = 0u, m1lo = 0u, m1hi = 0u;

    #pragma unroll 4
    for (int jj = 0; jj < jmax; ++jj) {
        const float sx = __int_as_float(__builtin_amdgcn_readlane(__float_as_int(bjv.x), jj));
        const float sy = __int_as_float(__builtin_amdgcn_readlane(__float_as_int(bjv.y), jj));
        const float sz = __int_as_float(__builtin_amdgcn_readlane(__float_as_int(bjv.z), jj));
        const float sw = __int_as_float(__builtin_amdgcn_readlane(__float_as_int(bjv.w), jj));
        const float sa = __int_as_float(__builtin_amdgcn_readlane(__float_as_int(av), jj));
        // row 0
        {
            float y1 = fmaxf(b0.x, sx);
            float x1 = fmaxf(b0.y, sy);
            float y2 = fminf(b0.z, sz);
            float x2 = fminf(b0.w, sw);
            float inter = fmaxf(y2 - y1, 0.0f) * fmaxf(x2 - x1, 0.0f);
            float uni = (a0 + sa) - inter;               // same assoc as reference
            float u = fmaxf(uni, 1e-8f);
            bool sup = ((double)inter >= C * (double)u); // == (inter/u > 0.8f) exactly
            if (d0) sup = sup && (lane < jj);            // strict j > i on diagonal
            unsigned int s = sup ? 1u : 0u;
            if (jj < 32) m0lo |= (s << jj); else m0hi |= (s << (jj - 32));
        }
        // row 1
        if (evalR1) {
            float y1 = fmaxf(b1.x, sx);
            float x1 = fmaxf(b1.y, sy);
            float y2 = fminf(b1.z, sz);
            float x2 = fminf(b1.w, sw);
            float inter = fmaxf(y2 - y1, 0.0f) * fmaxf(x2 - x1, 0.0f);
            float uni = (a1 + sa) - inter;
            float u = fmaxf(uni, 1e-8f);
            bool sup = ((double)inter >= C * (double)u);
            if (d1) sup = sup && (lane < jj);
            unsigned int s = sup ? 1u : 0u;
            if (jj < 32) m1lo |= (s << jj); else m1hi |= (s << (jj - 32));
        }
    }

    const unsigned long long w0 =
        ((unsigned long long)m0hi << 32) | (unsigned long long)m0lo;
    if (d0) {
        mdiag[((size_t)b << 10) + (W << 6) + lane] = w0;
    } else {
        const int I0 = 2 * RG;
        const int cg0 = 15 * I0 - (I0 * (I0 - 1)) / 2 + (W - I0 - 1);
        mtri[(size_t)b * TRI_WORDS + (size_t)cg0 * TRIP + lane] = w0;
    }
    if (evalR1 && r1 < PRE) {
        const unsigned long long w1 =
            ((unsigned long long)m1hi << 32) | (unsigned long long)m1lo;
        if (d1) {
            mdiag[((size_t)b << 10) + (W << 6) + lane] = w1;   // r1&63 == lane
        } else {
            const int I1 = 2 * RG + 1;
            const int cg1 = 15 * I1 - (I1 * (I1 - 1)) / 2 + (W - I1 - 1);
            mtri[(size_t)b * TRI_WORDS + (size_t)cg1 * TRIP + lane] = w1;
        }
    }
}

// ---------------- K3: ffs-driven greedy scan + output ----------------
// Stage tri (62.4KB) + diag (8KB) mask blocks into LDS with linear float4 copies.
// Wave0 scans: first alive row is always kept -> iterate only kept rows (<=256,
// early stop). Flush reads kept rows from sidx (LDS) -> pure LDS gathers; all
// readlane indices are uniform (literal or readfirstlane'd) -> no waterfalls.
__global__ __launch_bounds__(512) void k_nms_out(
    const float4* __restrict__ tboxes,
    const float* __restrict__ tscores,
    const unsigned long long* __restrict__ mtri,
    const unsigned long long* __restrict__ mdiag,
    float* __restrict__ out)   // [B*POST*4] boxes then [B*POST] scores
{
    #pragma clang fp contract(off)
    const int b = blockIdx.x;
    const int tid = threadIdx.x;
    __shared__ __align__(16) unsigned long long Ml[TRI_WORDS];   // 62,400 B
    __shared__ __align__(16) unsigned long long Mdl[NW * 64];    //  8,192 B
    __shared__ int sidx[POST];
    __shared__ int s_kc;

    // wave0: diagonal words into registers (coalesced 512B loads; scan-path readlane)
    unsigned int dlo[NW], dhi[NW];
    if (tid < 64) {
        const unsigned long long* Db = mdiag + ((size_t)b << 10);
        #pragma unroll
        for (int W = 0; W < NW; ++W) {
            const int base = W << 6;
            const int nvalid = (PRE - base < 64) ? (PRE - base) : 64;
            unsigned long long dv = Db[base + tid];
            if (tid >= nvalid) dv = 0ull;
            dlo[W] = (unsigned int)dv;
            dhi[W] = (unsigned int)(dv >> 32);
        }
    }

    // all threads: linear coalesced staging of tri + diag blocks
    {
        const float4* src = (const float4*)(mtri + (size_t)b * TRI_WORDS);
        float4* dst = (float4*)Ml;
        for (int i = tid; i < TRI_WORDS / 2; i += 512) dst[i] = src[i];
        const float4* src2 = (const float4*)(mdiag + ((size_t)b << 10));
        float4* dst2 = (float4*)Mdl;
        for (int i = tid; i < (NW * 64) / 2; i += 512) dst2[i] = src2[i];
    }
    __syncthreads();

    if (tid < 64) {
        const int lane = tid;
        const int wword = lane & 15;
        const int wgrp  = lane >> 4;
        unsigned long long rm = 0ull;   // distributed removed word (l&15), group partial
        int kc = 0;
        bool done = false;
        #pragma unroll
        for (int W = 0; W < NW; ++W) {
            const int base = W << 6;
            // merge the 4 group partials of removed word W -> uniform (literal lane idx)
            unsigned int rlo = (unsigned int)__builtin_amdgcn_readlane((int)(unsigned int)rm, W)
                             | (unsigned int)__builtin_amdgcn_readlane((int)(unsigned int)rm, W + 16)
                             | (unsigned int)__builtin_amdgcn_readlane((int)(unsigned int)rm, W + 32)
                             | (unsigned int)__builtin_amdgcn_readlane((int)(unsigned int)rm, W + 48);
            unsigned int rhi = (unsigned int)__builtin_amdgcn_readlane((int)(unsigned int)(rm >> 32), W)
                             | (unsigned int)__builtin_amdgcn_readlane((int)(unsigned int)(rm >> 32), W + 16)
                             | (unsigned int)__builtin_amdgcn_readlane((int)(unsigned int)(rm >> 32), W + 32)
                             | (unsigned int)__builtin_amdgcn_readlane((int)(unsigned int)(rm >> 32), W + 48);
            unsigned long long rmW = ((unsigned long long)rhi << 32) | (unsigned long long)rlo;
            unsigned long long valid = (PRE - base >= 64) ? ~0ull : ((1ull << (PRE - base)) - 1ull);
            unsigned long long alive = ~rmW & valid;
            const int k0 = kc;
            while (alive) {
                int i = __builtin_amdgcn_readfirstlane(__ffsll(alive) - 1);  // uniform
                if (lane == 0) sidx[kc] = base + i;
                ++kc;
                if (kc == POST) { done = true; break; }
                unsigned int dl = (unsigned int)__builtin_amdgcn_readlane((int)dlo[W], i);
                unsigned int dh = (unsigned int)__builtin_amdgcn_readlane((int)dhi[W], i);
                unsigned long long d = ((unsigned long long)dh << 32) | (unsigned long long)dl;
                alive &= ~(d | (1ull << i));
            }
            if (done) break;
            // flush kept rows sidx[k0..kc): 4 rows/round (one per group), pure LDS
            const int cgW = 15 * W - (W * (W - 1)) / 2;   // compile-time (W unrolled)
            for (int fp = k0; fp < kc; fp += 4) {
                const int idx = fp + wgrp;
                unsigned long long m = 0ull;
                if (idx < kc) {
                    const int ii = sidx[idx] & 63;
                    if (wword > W)       m = Ml[(cgW + wword - W - 1) * TRIP + ii];
                    else if (wword == W) m = Mdl[(W << 6) + ii];
                }
                rm |= m;
            }
        }
        if (lane == 0) s_kc = kc;
    }
    __syncthreads();

    const int kc = s_kc;
    const float4* bb = tboxes + (size_t)b * PRE;
    const float* ss = tscores + (size_t)b * PRE;
    float4* oB = (float4*)out + (size_t)b * POST;
    float* oS = out + (size_t)BATCH * POST * 4 + (size_t)b * POST;
    for (int t2 = tid; t2 < POST; t2 += 512) {
        float4 v = make_float4(0.f, 0.f, 0.f, 0.f);
        float sc = 0.f;
        if (t2 < kc) {
            int r = sidx[t2];
            float4 bx = bb[r];
            v.x = fminf(fmaxf(bx.x, 0.f), 1.f);
            v.y = fminf(fmaxf(bx.y, 0.f), 1.f);
            v.z = fminf(fmaxf(bx.z, 0.f), 1.f);
            v.w = fminf(fmaxf(bx.w, 0.f), 1.f);
            sc = ss[r];
        }
        oB[t2] = v;
        oS[t2] = sc;
    }
}

extern "C" void kernel_launch(void* const* d_in, const int* in_sizes, int n_in,
                              void* d_out, int out_size, void* d_ws, size_t ws_size,
                              hipStream_t stream) {
    const float* deltas  = (const float*)d_in[0];   // [64,8649,4] f32
    const float* probs   = (const float*)d_in[1];   // [64,8649]   f32
    const float* anchors = (const float*)d_in[3];   // [8649,4]    f32
    float* out = (float*)d_out;

    char* ws = (char*)d_ws;
    float4* tboxes = (float4*)ws;                                    // 1,024,000 B
    float* tscores = (float*)(ws + 1024000);                         //   256,000 B
    unsigned long long* mdiag = (unsigned long long*)(ws + 1280000); //   524,288 B
    unsigned long long* mtri  = (unsigned long long*)(ws + 1804288); // 3,993,600 B

    k_topk_decode<<<dim3(BATCH), dim3(1024), 0, stream>>>(deltas, probs, anchors,
                                                          tboxes, tscores);
    k_masks<<<dim3(18, BATCH), dim3(256), 0, stream>>>(tboxes, mtri, mdiag);
    k_nms_out<<<dim3(BATCH), dim3(512), 0, stream>>>(tboxes, tscores, mtri, mdiag, out);
}

// Round 12
// 89.369 us; speedup vs baseline: 1.0571x; 1.0258x over previous
//
#include <hip/hip_runtime.h>
#include <math.h>

#define BATCH 64
#define A_TOTAL 8649
#define PRE 1000
#define POST 256
#define NBINS 4096
#define NW 16              // 1000 bits -> 16 u64 words
#define TRIG 120           // upper-tri-minus-diag column groups: sum_{I=0..14}(15-I)
#define TRIP 65            // padded group stride (bank-conflict-free flush reads)
#define TRI_WORDS (TRIG * TRIP)   // 7800 u64 per batch

// ---------------- K1: per-batch exact top-1000 + box decode ----------------
// Histogram -> per-bin exact suffix counts (exc) -> threshold bin -> bin-grouped
// compaction -> rank = exc[bin] + within-bin count (segments small) -> decode
// + scatter to tboxes/tscores/tareas[b][rank]. Keys unique -> deterministic.
__global__ __launch_bounds__(1024) void k_topk_decode(
    const float* __restrict__ deltas,   // [B][A][4]
    const float* __restrict__ probs,    // [B][A]
    const float* __restrict__ anchors,  // [A][4] yxyx
    float4* __restrict__ tboxes,        // [B][PRE]
    float* __restrict__ tscores,        // [B][PRE]
    float* __restrict__ tareas)         // [B][PRE]
{
    #pragma clang fp contract(off)
    const int b = blockIdx.x;
    const int t = threadIdx.x;
    __shared__ unsigned int hist[NBINS];   // reused as per-bin scatter counters
    __shared__ unsigned int exc[NBINS];    // # anchors with bin' > bin
    __shared__ unsigned int sbits[A_TOTAL];
    __shared__ unsigned long long cand[2048];
    __shared__ unsigned int gsum[256];
    __shared__ unsigned int s_thr;
    __shared__ unsigned int s_n;

    for (int i = t; i < NBINS; i += 1024) hist[i] = 0u;
    __syncthreads();

    const float* pr = probs + (size_t)b * A_TOTAL;
    for (int i = t; i < A_TOTAL; i += 1024) {
        unsigned int bits = __float_as_uint(pr[i]);   // probs in [0,1): bit order == value order
        sbits[i] = bits;
        atomicAdd(&hist[bits >> 18], 1u);
    }
    __syncthreads();

    // 16-bin group partial sums
    if (t < 256) {
        unsigned int gs = 0;
        #pragma unroll
        for (int q = 0; q < 16; ++q) gs += hist[t * 16 + q];
        gsum[t] = gs;
    }
    __syncthreads();
    // single-wave inclusive suffix scan over 256 groups (4 groups per lane)
    if (t < 64) {
        const int l = t;
        unsigned int a  = gsum[4 * l];
        unsigned int b2 = gsum[4 * l + 1];
        unsigned int c  = gsum[4 * l + 2];
        unsigned int d  = gsum[4 * l + 3];
        unsigned int quad = a + b2 + c + d;
        unsigned int q = quad;
        #pragma unroll
        for (int off = 1; off < 64; off <<= 1) {
            unsigned int v = __shfl_down(q, off);
            q += (l + off < 64) ? v : 0u;
        }
        gsum[4 * l]     = q;
        gsum[4 * l + 1] = q - a;
        gsum[4 * l + 2] = q - a - b2;
        gsum[4 * l + 3] = q - a - b2 - c;
    }
    __syncthreads();
    // per-bin exclusive suffix counts
    if (t < 256) {
        unsigned int run = (t == 255) ? 0u : gsum[t + 1];
        for (int q = 15; q >= 0; --q) {
            int bin = t * 16 + q;
            exc[bin] = run;
            run += hist[bin];
        }
    }
    __syncthreads();
    // threshold bin T = max bin with (exc+hist) >= PRE; n = candidates at/above T
    for (int bin = t; bin < NBINS; bin += 1024) {
        unsigned int ge = exc[bin] + hist[bin];
        unsigned int ge1 = (bin == NBINS - 1) ? 0u : (exc[bin + 1] + hist[bin + 1]);
        if (ge >= PRE && ge1 < PRE) { s_thr = (unsigned int)bin; s_n = ge; }
    }
    __syncthreads();
    const unsigned int T = s_thr;
    const int n = (s_n > 2048u) ? 2048 : (int)s_n;
    // reuse hist as per-bin scatter counters
    for (int i = t; i < NBINS; i += 1024) hist[i] = 0u;
    __syncthreads();

    // bin-grouped compaction: bin k's candidates land in [exc[k], exc[k]+cnt[k])
    for (int i = t; i < A_TOTAL; i += 1024) {
        unsigned int bits = sbits[i];
        unsigned int bin = bits >> 18;
        if (bin >= T) {
            unsigned int p = exc[bin] + atomicAdd(&hist[bin], 1u);
            if (p < 2048u)
                cand[p] = ((unsigned long long)bits << 32) |
                          (unsigned long long)(0xFFFFFFFFu - (unsigned int)i);
        }
    }
    __syncthreads();

    // rank within segment + decode + scatter
    const float4* anc4 = (const float4*)anchors;
    const float4* dl4  = (const float4*)(deltas + (size_t)b * A_TOTAL * 4);
    for (int p = t; p < n; p += 1024) {
        unsigned long long key = cand[p];
        unsigned int bin = (unsigned int)(key >> 50);       // score_bits >> 18
        int segs = (int)exc[bin];
        int sege = (bin > 0) ? (int)exc[bin - 1] : n;       // exc[b-1] == exc[b]+hist_orig[b]
        if (sege > 2048) sege = 2048;
        unsigned int rank = (unsigned int)segs;
        for (int q = segs; q < sege; ++q) rank += (cand[q] > key);
        if (rank >= PRE) continue;
        unsigned int idx = 0xFFFFFFFFu - (unsigned int)(key & 0xFFFFFFFFull);
        float sc = __uint_as_float((unsigned int)(key >> 32));
        float4 a = anc4[idx];
        float4 d = dl4[idx];
        float ah  = a.z - a.x;
        float aw  = a.w - a.y;
        float acy = a.x + 0.5f * ah;
        float acx = a.y + 0.5f * aw;
        float ty = d.x * 0.1f, tx = d.y * 0.1f, th = d.z * 0.2f, tw = d.w * 0.2f;
        float h = (float)exp((double)th) * ah;
        float w = (float)exp((double)tw) * aw;
        float cy = ty * ah + acy;
        float cx = tx * aw + acx;
        float4 bx = make_float4(cy - 0.5f * h, cx - 0.5f * w, cy + 0.5f * h, cx + 0.5f * w);
        tboxes[(size_t)b * PRE + rank] = bx;
        tscores[(size_t)b * PRE + rank] = sc;
        tareas[(size_t)b * PRE + rank] = (bx.z - bx.x) * (bx.w - bx.y);
    }
}

// ---------------- K2: suppression bitmask build (64x64 tiles, no LDS) ----------------
// lane = row; j-side operands are wave-uniform -> broadcast loads from global.
// Off-diag tile (I,W) stores to compact tri layout mtri[b][(CG(I)+(W-I-1))*65+lane];
// diag tile W stores mdiag[b][W*64+lane]. Both coalesced.
// Decision equivalence: RN(inter/u) > 0.8f  <=>  inter >= (0.8f + 2^-25) * u
// (0.8f has odd mantissa -> halfway rounds up; 25x24-bit double product exact).
__global__ __launch_bounds__(256) void k_masks(
    const float4* __restrict__ tboxes,          // [B][PRE]
    const float* __restrict__ tareas,           // [B][PRE]
    unsigned long long* __restrict__ mtri,      // [B][TRI_WORDS]
    unsigned long long* __restrict__ mdiag)     // [B][NW*64]
{
    #pragma clang fp contract(off)
    const int b = blockIdx.y;
    // tile id -> (I, W), upper triangle row-major: I has (16-I) tiles
    int f = blockIdx.x * 4 + (threadIdx.x >> 6);
    f = __builtin_amdgcn_readfirstlane(f);      // pin wave-uniform -> SGPR
    int I = 0;
    while (f >= 16 - I) { f -= 16 - I; ++I; }
    const int W = I + f;
    const int lane = threadIdx.x & 63;
    const int row = (I << 6) + lane;
    const int rr = (row < PRE) ? row : 0;
    const float4 bi = tboxes[(size_t)b * PRE + rr];
    const float areai = tareas[(size_t)b * PRE + rr];
    const float4* __restrict__ bjp = tboxes + (size_t)b * PRE + (W << 6);
    const float*  __restrict__ ajp = tareas + (size_t)b * PRE + (W << 6);
    const int jmax = (PRE - (W << 6) < 64) ? (PRE - (W << 6)) : 64;
    const double C = (double)0.8f + 0x1p-25;
    const bool diag = (I == W);
    unsigned int mlo = 0u, mhi = 0u;

#define IOU_SUP(jj, sup) do { \
        const float4 bj = bjp[jj]; \
        const float aj = ajp[jj]; \
        float y1 = fmaxf(bi.x, bj.x); \
        float x1 = fmaxf(bi.y, bj.y); \
        float y2 = fminf(bi.z, bj.z); \
        float x2 = fminf(bi.w, bj.w); \
        float inter = fmaxf(y2 - y1, 0.0f) * fmaxf(x2 - x1, 0.0f); \
        float uni = (areai + aj) - inter;            /* same assoc as reference */ \
        float u = fmaxf(uni, 1e-8f); \
        sup = ((double)inter >= C * (double)u);      /* == (inter/u > 0.8f) exactly */ \
        if (diag) sup = sup && (lane < (jj)); \
    } while (0)

    if (jmax == 64) {
        #pragma unroll 4
        for (int jj = 0; jj < 32; ++jj) {
            bool sup; IOU_SUP(jj, sup);
            mlo |= sup ? (1u << jj) : 0u;
        }
        #pragma unroll 4
        for (int jj = 32; jj < 64; ++jj) {
            bool sup; IOU_SUP(jj, sup);
            mhi |= sup ? (1u << (jj - 32)) : 0u;
        }
    } else {
        for (int jj = 0; jj < jmax; ++jj) {
            bool sup; IOU_SUP(jj, sup);
            unsigned int s = sup ? (1u << (jj & 31)) : 0u;
            if (jj < 32) mlo |= s; else mhi |= s;
        }
    }
#undef IOU_SUP
    const unsigned long long mword =
        ((unsigned long long)mhi << 32) | (unsigned long long)mlo;
    if (row < PRE) {
        if (diag) {
            mdiag[((size_t)b << 10) + (W << 6) + lane] = mword;
        } else {
            const int cg = 15 * I - (I * (I - 1)) / 2 + (W - I - 1);
            mtri[(size_t)b * TRI_WORDS + (size_t)cg * TRIP + lane] = mword;
        }
    }
}

// ---------------- K3: ffs-driven greedy scan + output ----------------
// Stage the compact tri mask block (62.4KB) into LDS with a linear float4 copy;
// diagonal words -> wave0 registers (coalesced 512B loads). Wave0 scans: first
// alive row is always kept -> iterate only kept rows (<=256 with early stop).
__global__ __launch_bounds__(512) void k_nms_out(
    const float4* __restrict__ tboxes,
    const float* __restrict__ tscores,
    const unsigned long long* __restrict__ mtri,
    const unsigned long long* __restrict__ mdiag,
    float* __restrict__ out)   // [B*POST*4] boxes then [B*POST] scores
{
    #pragma clang fp contract(off)
    const int b = blockIdx.x;
    const int tid = threadIdx.x;
    __shared__ __align__(16) unsigned long long Ml[TRI_WORDS];   // 62,400 B
    __shared__ int sidx[POST];
    __shared__ int s_kc;

    // wave0: diagonal words, lane l -> row W*64+l's word W (coalesced per W)
    unsigned int dlo[NW], dhi[NW];
    if (tid < 64) {
        const int lane = tid;
        const unsigned long long* Db = mdiag + ((size_t)b << 10);
        #pragma unroll
        for (int W = 0; W < NW; ++W) {
            const int base = W << 6;
            const int nvalid = (PRE - base < 64) ? (PRE - base) : 64;
            unsigned long long dv = Db[base + lane];
            if (lane >= nvalid) dv = 0ull;
            dlo[W] = (unsigned int)dv;
            dhi[W] = (unsigned int)(dv >> 32);
        }
    }

    // all threads: linear coalesced copy of the tri block (3900 float4)
    {
        const float4* src = (const float4*)(mtri + (size_t)b * TRI_WORDS);
        float4* dst = (float4*)Ml;
        for (int idx = tid; idx < TRI_WORDS / 2; idx += 512) dst[idx] = src[idx];
    }
    __syncthreads();

    if (tid < 64) {
        const int lane = tid;
        const int wword = lane & 15;
        const int wgrp  = lane >> 4;
        unsigned long long rm = 0ull;   // distributed removed word (l&15), group partial
        int kc = 0;
        bool done = false;
        #pragma unroll
        for (int W = 0; W < NW; ++W) {
            const int base = W << 6;
            // merge the 4 group partials of removed word W -> uniform
            unsigned int rlo = (unsigned int)__builtin_amdgcn_readlane((int)(unsigned int)rm, W)
                             | (unsigned int)__builtin_amdgcn_readlane((int)(unsigned int)rm, W + 16)
                             | (unsigned int)__builtin_amdgcn_readlane((int)(unsigned int)rm, W + 32)
                             | (unsigned int)__builtin_amdgcn_readlane((int)(unsigned int)rm, W + 48);
            unsigned int rhi = (unsigned int)__builtin_amdgcn_readlane((int)(unsigned int)(rm >> 32), W)
                             | (unsigned int)__builtin_amdgcn_readlane((int)(unsigned int)(rm >> 32), W + 16)
                             | (unsigned int)__builtin_amdgcn_readlane((int)(unsigned int)(rm >> 32), W + 32)
                             | (unsigned int)__builtin_amdgcn_readlane((int)(unsigned int)(rm >> 32), W + 48);
            unsigned long long rmW = ((unsigned long long)rhi << 32) | (unsigned long long)rlo;
            unsigned long long valid = (PRE - base >= 64) ? ~0ull : ((1ull << (PRE - base)) - 1ull);
            unsigned long long alive = ~rmW & valid;
            unsigned long long keptw = 0ull;
            while (alive) {
                int i = __builtin_amdgcn_readfirstlane(__ffsll(alive) - 1);
                keptw |= (1ull << i);
                if (lane == 0) sidx[kc] = base + i;
                ++kc;
                if (kc == POST) { done = true; break; }
                unsigned int dl = (unsigned int)__builtin_amdgcn_readlane((int)dlo[W], i);
                unsigned int dh = (unsigned int)__builtin_amdgcn_readlane((int)dhi[W], i);
                unsigned long long d = ((unsigned long long)dh << 32) | (unsigned long long)dl;
                alive &= ~(d | (1ull << i));
            }
            if (done) break;
            // flush kept rows' masks into distributed rm; 8 rows per round (A+B)
            const int cgW = 15 * W - (W * (W - 1)) / 2;   // compile-time (W unrolled)
            unsigned long long kw = keptw;
            while (kw) {
                unsigned long long tA = kw;
                if (wgrp > 0) tA &= tA - 1ull;
                if (wgrp > 1) tA &= tA - 1ull;
                if (wgrp > 2) tA &= tA - 1ull;
                const bool vA = (tA != 0ull);
                const int iA = vA ? (__ffsll(tA) - 1) : 0;
                unsigned long long kw2 = kw;
                kw2 &= kw2 - 1ull; kw2 &= kw2 - 1ull; kw2 &= kw2 - 1ull; kw2 &= kw2 - 1ull;
                unsigned long long tB = kw2;
                if (wgrp > 0) tB &= tB - 1ull;
                if (wgrp > 1) tB &= tB - 1ull;
                if (wgrp > 2) tB &= tB - 1ull;
                const bool vB = (tB != 0ull);
                const int iB = vB ? (__ffsll(tB) - 1) : 0;
                kw = kw2;
                kw &= kw - 1ull; kw &= kw - 1ull; kw &= kw - 1ull; kw &= kw - 1ull;
                // lane's word for row i{A,B}: wword>W -> LDS tri; ==W -> diag regs; <W -> 0
                unsigned long long lA = 0ull, lB = 0ull;
                if (wword > W) {
                    const int col = cgW + (wword - W - 1);
                    lA = Ml[col * TRIP + iA];
                    lB = Ml[col * TRIP + iB];
                }
                unsigned long long gA =
                    ((unsigned long long)(unsigned int)__builtin_amdgcn_readlane((int)dhi[W], iA) << 32)
                  |  (unsigned long long)(unsigned int)__builtin_amdgcn_readlane((int)dlo[W], iA);
                unsigned long long gB =
                    ((unsigned long long)(unsigned int)__builtin_amdgcn_readlane((int)dhi[W], iB) << 32)
                  |  (unsigned long long)(unsigned int)__builtin_amdgcn_readlane((int)dlo[W], iB);
                unsigned long long mA = (wword > W) ? lA : ((wword == W) ? gA : 0ull);
                unsigned long long mB = (wword > W) ? lB : ((wword == W) ? gB : 0ull);
                if (!vA) mA = 0ull;
                if (!vB) mB = 0ull;
                rm |= mA | mB;
            }
        }
        if (tid == 0) s_kc = kc;
    }
    __syncthreads();

    const int kc = s_kc;
    const float4* bb = tboxes + (size_t)b * PRE;
    const float* ss = tscores + (size_t)b * PRE;
    float4* oB = (float4*)out + (size_t)b * POST;
    float* oS = out + (size_t)BATCH * POST * 4 + (size_t)b * POST;
    for (int t2 = tid; t2 < POST; t2 += 512) {
        float4 v = make_float4(0.f, 0.f, 0.f, 0.f);
        float sc = 0.f;
        if (t2 < kc) {
            int r = sidx[t2];
            float4 bx = bb[r];
            v.x = fminf(fmaxf(bx.x, 0.f), 1.f);
            v.y = fminf(fmaxf(bx.y, 0.f), 1.f);
            v.z = fminf(fmaxf(bx.z, 0.f), 1.f);
            v.w = fminf(fmaxf(bx.w, 0.f), 1.f);
            sc = ss[r];
        }
        oB[t2] = v;
        oS[t2] = sc;
    }
}

extern "C" void kernel_launch(void* const* d_in, const int* in_sizes, int n_in,
                              void* d_out, int out_size, void* d_ws, size_t ws_size,
                              hipStream_t stream) {
    const float* deltas  = (const float*)d_in[0];   // [64,8649,4] f32
    const float* probs   = (const float*)d_in[1];   // [64,8649]   f32
    const float* anchors = (const float*)d_in[3];   // [8649,4]    f32
    float* out = (float*)d_out;

    char* ws = (char*)d_ws;
    float4* tboxes = (float4*)ws;                                    // 1,024,000 B
    float* tscores = (float*)(ws + 1024000);                         //   256,000 B
    float* tareas  = (float*)(ws + 1280000);                         //   256,000 B
    unsigned long long* mdiag = (unsigned long long*)(ws + 1536000); //   524,288 B
    unsigned long long* mtri  = (unsigned long long*)(ws + 2060288); // 3,993,600 B

    k_topk_decode<<<dim3(BATCH), dim3(1024), 0, stream>>>(deltas, probs, anchors,
                                                          tboxes, tscores, tareas);
    k_masks<<<dim3(34, BATCH), dim3(256), 0, stream>>>(tboxes, tareas, mtri, mdiag);
    k_nms_out<<<dim3(BATCH), dim3(512), 0, stream>>>(tboxes, tscores, mtri, mdiag, out);
}